// Round 1
// baseline (1132.882 us; speedup 1.0000x reference)
//
#include <hip/hip_runtime.h>
#include <math.h>

#define DMODEL 1024
#define NHEADS 16
#define DKH    64
#define BATCH  2
#define SEQ    2048

// ---------------------------------------------------------------------------
// Kernel 1: fused QKV projection.  out = x @ W + b for W in {Wq,Wk,Wv},
// scattered directly into (B, H, T, Dk) layout so attention reads contiguous.
// BM=BN=64, BK=16, 256 threads, 4x4 micro-tile per thread.
// ---------------------------------------------------------------------------
__global__ __launch_bounds__(256) void qkv_gemm(
    const float* __restrict__ x,
    const float* __restrict__ Wq, const float* __restrict__ bq,
    const float* __restrict__ Wk, const float* __restrict__ bk,
    const float* __restrict__ Wv, const float* __restrict__ bv,
    float* __restrict__ Qo, float* __restrict__ Ko, float* __restrict__ Vo)
{
    const int which = blockIdx.z;
    const float* __restrict__ W    = (which == 0) ? Wq : (which == 1) ? Wk : Wv;
    const float* __restrict__ bias = (which == 0) ? bq : (which == 1) ? bk : bv;
    float* __restrict__ out        = (which == 0) ? Qo : (which == 1) ? Ko : Vo;

    __shared__ float As[16][64];   // As[k][m]  (transposed x tile)
    __shared__ float Bs[16][64];   // Bs[k][n]

    const int i0  = blockIdx.x * 64;     // row base into (B*T)
    const int n0  = blockIdx.y * 64;     // col base (== head * 64)
    const int tid = threadIdx.x;
    const int tx  = tid & 15;
    const int ty  = tid >> 4;

    // loaders
    const int am  = tid >> 2;            // 0..63 row in A tile
    const int ak  = (tid & 3) << 2;      // 0,4,8,12
    const int bkr = tid >> 4;            // 0..15 k row in B tile
    const int bn  = (tid & 15) << 2;     // col in B tile

    float acc[4][4] = {};

    for (int k0 = 0; k0 < DMODEL; k0 += 16) {
        float4 av  = *(const float4*)(x + (size_t)(i0 + am) * DMODEL + k0 + ak);
        float4 bv4 = *(const float4*)(W + (size_t)(k0 + bkr) * DMODEL + n0 + bn);
        As[ak + 0][am] = av.x;
        As[ak + 1][am] = av.y;
        As[ak + 2][am] = av.z;
        As[ak + 3][am] = av.w;
        *(float4*)&Bs[bkr][bn] = bv4;
        __syncthreads();
#pragma unroll
        for (int k = 0; k < 16; ++k) {
            float4 a4 = *(const float4*)&As[k][ty << 2];
            float4 b4 = *(const float4*)&Bs[k][tx << 2];
            float a[4] = {a4.x, a4.y, a4.z, a4.w};
            float b[4] = {b4.x, b4.y, b4.z, b4.w};
#pragma unroll
            for (int i = 0; i < 4; ++i)
#pragma unroll
                for (int j = 0; j < 4; ++j)
                    acc[i][j] += a[i] * b[j];
        }
        __syncthreads();
    }

    const int h = n0 >> 6;               // BN==64 == head width
    float bb[4];
#pragma unroll
    for (int j = 0; j < 4; ++j) bb[j] = bias[n0 + (tx << 2) + j];

#pragma unroll
    for (int i = 0; i < 4; ++i) {
        int row  = i0 + (ty << 2) + i;
        int bidx = row >> 11;            // / SEQ
        int t    = row & (SEQ - 1);
        float4 r;
        r.x = acc[i][0] + bb[0];
        r.y = acc[i][1] + bb[1];
        r.z = acc[i][2] + bb[2];
        r.w = acc[i][3] + bb[3];
        *(float4*)(out + ((((size_t)bidx * NHEADS + h) * SEQ + t) << 6) + (tx << 2)) = r;
    }
}

// ---------------------------------------------------------------------------
// Kernel 2: flash-style causal attention.  One block = one (b, h, 64-row Q
// tile).  Online softmax; P goes through LDS (aliased onto the K buffer) so
// the PV product can reduce over all 64 keys.
// Writes attn output in (B, T, C) layout for the final projection.
// ---------------------------------------------------------------------------
__global__ __launch_bounds__(256) void attn_kernel(
    const float* __restrict__ Q, const float* __restrict__ K,
    const float* __restrict__ V, float* __restrict__ AO)
{
    const int qt  = blockIdx.x;          // 0..31
    const int h   = blockIdx.y;
    const int b   = blockIdx.z;
    const int tid = threadIdx.x;
    const int tx  = tid & 15;
    const int ty  = tid >> 4;

    __shared__ float Qs[64][65];         // padded: scalar reads 2-way max
    __shared__ float KPs[64][65];        // K tile, then reused for P tile
    __shared__ float Vs[64][64];         // unpadded: float4 writes, 2-way reads

    const int lr = tid >> 2;             // loader row 0..63
    const int lc = (tid & 3) << 4;       // loader col {0,16,32,48}

    const size_t headbase = ((size_t)b * NHEADS + h) * SEQ;

    {   // stage Q tile once
        const float* qg = Q + ((headbase + qt * 64 + lr) << 6) + lc;
#pragma unroll
        for (int u = 0; u < 4; ++u) {
            float4 v = *(const float4*)(qg + u * 4);
            Qs[lr][lc + u * 4 + 0] = v.x;
            Qs[lr][lc + u * 4 + 1] = v.y;
            Qs[lr][lc + u * 4 + 2] = v.z;
            Qs[lr][lc + u * 4 + 3] = v.w;
        }
    }

    float m_i[4], l_i[4], o[4][4];
#pragma unroll
    for (int i = 0; i < 4; ++i) {
        m_i[i] = -INFINITY;
        l_i[i] = 0.f;
#pragma unroll
        for (int j = 0; j < 4; ++j) o[i][j] = 0.f;
    }

    for (int kt = 0; kt <= qt; ++kt) {
        __syncthreads();   // prev PV done (and Qs staged, first iter)
        {
            const float* kg = K + ((headbase + kt * 64 + lr) << 6) + lc;
            const float* vg = V + ((headbase + kt * 64 + lr) << 6) + lc;
#pragma unroll
            for (int u = 0; u < 4; ++u) {
                float4 kv = *(const float4*)(kg + u * 4);
                KPs[lr][lc + u * 4 + 0] = kv.x;
                KPs[lr][lc + u * 4 + 1] = kv.y;
                KPs[lr][lc + u * 4 + 2] = kv.z;
                KPs[lr][lc + u * 4 + 3] = kv.w;
                *(float4*)&Vs[lr][lc + u * 4] = *(const float4*)(vg + u * 4);
            }
        }
        __syncthreads();

        // S = Q @ K^T  (inner over d)
        float s[4][4] = {};
#pragma unroll 4
        for (int d = 0; d < 64; ++d) {
            float qv[4], kv[4];
#pragma unroll
            for (int i = 0; i < 4; ++i) qv[i] = Qs[(ty << 2) + i][d];
#pragma unroll
            for (int j = 0; j < 4; ++j) kv[j] = KPs[(tx << 2) + j][d];
#pragma unroll
            for (int i = 0; i < 4; ++i)
#pragma unroll
                for (int j = 0; j < 4; ++j)
                    s[i][j] += qv[i] * kv[j];
        }
        __syncthreads();   // all K reads done -> KPs reusable as P

        const bool diag = (kt == qt);
#pragma unroll
        for (int i = 0; i < 4; ++i) {
#pragma unroll
            for (int j = 0; j < 4; ++j) {
                s[i][j] *= 0.125f;   // 1/sqrt(64)
                if (diag && ((tx << 2) + j) > ((ty << 2) + i))
                    s[i][j] = -INFINITY;
            }
            // row max across the 16 tx threads (consecutive lanes)
            float mx = fmaxf(fmaxf(s[i][0], s[i][1]), fmaxf(s[i][2], s[i][3]));
#pragma unroll
            for (int off = 8; off >= 1; off >>= 1)
                mx = fmaxf(mx, __shfl_xor(mx, off, 16));
            float mn = fmaxf(m_i[i], mx);
            float p0 = __expf(s[i][0] - mn);
            float p1 = __expf(s[i][1] - mn);
            float p2 = __expf(s[i][2] - mn);
            float p3 = __expf(s[i][3] - mn);
            float rs = p0 + p1 + p2 + p3;
#pragma unroll
            for (int off = 8; off >= 1; off >>= 1)
                rs += __shfl_xor(rs, off, 16);
            float alpha = __expf(m_i[i] - mn);   // 0 on first tile
            l_i[i] = l_i[i] * alpha + rs;
            m_i[i] = mn;
#pragma unroll
            for (int j = 0; j < 4; ++j) o[i][j] *= alpha;
            KPs[(ty << 2) + i][(tx << 2) + 0] = p0;
            KPs[(ty << 2) + i][(tx << 2) + 1] = p1;
            KPs[(ty << 2) + i][(tx << 2) + 2] = p2;
            KPs[(ty << 2) + i][(tx << 2) + 3] = p3;
        }
        __syncthreads();   // P visible to all

        // O += P @ V  (inner over keys c)
#pragma unroll 4
        for (int c = 0; c < 64; ++c) {
            float vv[4];
#pragma unroll
            for (int j = 0; j < 4; ++j) vv[j] = Vs[c][(tx << 2) + j];
#pragma unroll
            for (int i = 0; i < 4; ++i) {
                float pv = KPs[(ty << 2) + i][c];
#pragma unroll
                for (int j = 0; j < 4; ++j) o[i][j] += pv * vv[j];
            }
        }
    }

    // epilogue: normalize and write (B, T, C)
#pragma unroll
    for (int i = 0; i < 4; ++i) {
        float inv = 1.0f / l_i[i];
        int t = qt * 64 + (ty << 2) + i;
        float4 r;
        r.x = o[i][0] * inv;
        r.y = o[i][1] * inv;
        r.z = o[i][2] * inv;
        r.w = o[i][3] * inv;
        *(float4*)(AO + ((size_t)b * SEQ + t) * DMODEL + h * 64 + (tx << 2)) = r;
    }
}

// ---------------------------------------------------------------------------
// Kernel 3: output projection.  out = AO @ Wo + bo, row-major (B, T, C).
// ---------------------------------------------------------------------------
__global__ __launch_bounds__(256) void out_gemm(
    const float* __restrict__ A, const float* __restrict__ W,
    const float* __restrict__ bias, float* __restrict__ out)
{
    __shared__ float As[16][64];
    __shared__ float Bs[16][64];

    const int i0  = blockIdx.x * 64;
    const int n0  = blockIdx.y * 64;
    const int tid = threadIdx.x;
    const int tx  = tid & 15;
    const int ty  = tid >> 4;

    const int am  = tid >> 2;
    const int ak  = (tid & 3) << 2;
    const int bkr = tid >> 4;
    const int bn  = (tid & 15) << 2;

    float acc[4][4] = {};

    for (int k0 = 0; k0 < DMODEL; k0 += 16) {
        float4 av  = *(const float4*)(A + (size_t)(i0 + am) * DMODEL + k0 + ak);
        float4 bv4 = *(const float4*)(W + (size_t)(k0 + bkr) * DMODEL + n0 + bn);
        As[ak + 0][am] = av.x;
        As[ak + 1][am] = av.y;
        As[ak + 2][am] = av.z;
        As[ak + 3][am] = av.w;
        *(float4*)&Bs[bkr][bn] = bv4;
        __syncthreads();
#pragma unroll
        for (int k = 0; k < 16; ++k) {
            float4 a4 = *(const float4*)&As[k][ty << 2];
            float4 b4 = *(const float4*)&Bs[k][tx << 2];
            float a[4] = {a4.x, a4.y, a4.z, a4.w};
            float b[4] = {b4.x, b4.y, b4.z, b4.w};
#pragma unroll
            for (int i = 0; i < 4; ++i)
#pragma unroll
                for (int j = 0; j < 4; ++j)
                    acc[i][j] += a[i] * b[j];
        }
        __syncthreads();
    }

    float bb[4];
#pragma unroll
    for (int j = 0; j < 4; ++j) bb[j] = bias[n0 + (tx << 2) + j];

#pragma unroll
    for (int i = 0; i < 4; ++i) {
        int row = i0 + (ty << 2) + i;
        float4 r;
        r.x = acc[i][0] + bb[0];
        r.y = acc[i][1] + bb[1];
        r.z = acc[i][2] + bb[2];
        r.w = acc[i][3] + bb[3];
        *(float4*)(out + (size_t)row * DMODEL + n0 + (tx << 2)) = r;
    }
}

// ---------------------------------------------------------------------------
extern "C" void kernel_launch(void* const* d_in, const int* in_sizes, int n_in,
                              void* d_out, int out_size, void* d_ws, size_t ws_size,
                              hipStream_t stream)
{
    const float* x  = (const float*)d_in[0];
    // d_in[1] = mask (causal tril) — implied by kernel structure, unused
    const float* Wq = (const float*)d_in[2];
    const float* bq = (const float*)d_in[3];
    const float* Wk = (const float*)d_in[4];
    const float* bk = (const float*)d_in[5];
    const float* Wv = (const float*)d_in[6];
    const float* bv = (const float*)d_in[7];
    const float* Wo = (const float*)d_in[8];
    const float* bo = (const float*)d_in[9];
    float* out = (float*)d_out;

    // workspace: Q, K, V in (B,H,T,Dk), AO in (B,T,C) — 4 x 16 MB = 64 MB
    const size_t QKV = (size_t)BATCH * NHEADS * SEQ * DKH;   // 4M floats
    float* ws = (float*)d_ws;
    float* Qb  = ws;
    float* Kb  = ws + QKV;
    float* Vb  = ws + 2 * QKV;
    float* AOb = ws + 3 * QKV;

    qkv_gemm<<<dim3((BATCH * SEQ) / 64, DMODEL / 64, 3), 256, 0, stream>>>(
        x, Wq, bq, Wk, bk, Wv, bv, Qb, Kb, Vb);

    attn_kernel<<<dim3(SEQ / 64, NHEADS, BATCH), 256, 0, stream>>>(
        Qb, Kb, Vb, AOb);

    out_gemm<<<dim3((BATCH * SEQ) / 64, DMODEL / 64), 256, 0, stream>>>(
        AOb, Wo, bo, out);
}

// Round 2
// 278.979 us; speedup vs baseline: 4.0608x; 4.0608x over previous
//
#include <hip/hip_runtime.h>
#include <math.h>

typedef unsigned short ushort_t;
typedef short short8 __attribute__((ext_vector_type(8)));
typedef float f32x4 __attribute__((ext_vector_type(4)));

#define DMODEL 1024
#define NHEADS 16
#define DKH    64
#define BATCH  2
#define SEQ    2048
#define BT     (BATCH * SEQ)   // 4096

#define GBM 128
#define GBN 128
#define GBK 32

__device__ __forceinline__ ushort_t f2bf(float f) {
    union { float f; unsigned u; } a; a.f = f;
    return (ushort_t)((a.u + 0x7FFFu + ((a.u >> 16) & 1u)) >> 16);
}

__device__ __forceinline__ void async_copy16(const ushort_t* g, ushort_t* l) {
    __builtin_amdgcn_global_load_lds(
        (__attribute__((address_space(1))) void*)g,
        (__attribute__((address_space(3))) void*)l, 16, 0, 0);
}

// ---------------------------------------------------------------------------
// cast x (fp32 row-major) -> bf16 row-major
// ---------------------------------------------------------------------------
__global__ __launch_bounds__(256) void cast_x_kernel(
    const float* __restrict__ x, ushort_t* __restrict__ xb)
{
    size_t i = ((size_t)blockIdx.x * 256 + threadIdx.x) * 8;
    float4 a = *(const float4*)(x + i);
    float4 b = *(const float4*)(x + i + 4);
    union { ushort_t u[8]; short8 v; } r;
    r.u[0] = f2bf(a.x); r.u[1] = f2bf(a.y); r.u[2] = f2bf(a.z); r.u[3] = f2bf(a.w);
    r.u[4] = f2bf(b.x); r.u[5] = f2bf(b.y); r.u[6] = f2bf(b.z); r.u[7] = f2bf(b.w);
    *(short8*)(xb + i) = r.v;
}

// ---------------------------------------------------------------------------
// cast + transpose weights: W (K x N fp32) -> WT (N x K bf16)
// ---------------------------------------------------------------------------
__global__ __launch_bounds__(256) void wtrans_kernel(
    const float* __restrict__ Wq, const float* __restrict__ Wk,
    const float* __restrict__ Wv, const float* __restrict__ Wo,
    ushort_t* __restrict__ WqT, ushort_t* __restrict__ WkT,
    ushort_t* __restrict__ WvT, ushort_t* __restrict__ WoT)
{
    const int z = blockIdx.z;
    const float* W = (z == 0) ? Wq : (z == 1) ? Wk : (z == 2) ? Wv : Wo;
    ushort_t*   WT = (z == 0) ? WqT : (z == 1) ? WkT : (z == 2) ? WvT : WoT;

    __shared__ ushort_t tile[64][72];
    const int k0 = blockIdx.x * 64, n0 = blockIdx.y * 64;
    const int tid = threadIdx.x;

    const int r  = tid >> 2;
    const int cb = (tid & 3) * 16;
#pragma unroll
    for (int u = 0; u < 4; ++u) {
        float4 v = *(const float4*)(W + (size_t)(k0 + r) * DMODEL + n0 + cb + u * 4);
        union { ushort_t u4[4]; unsigned long long ll; } p;
        p.u4[0] = f2bf(v.x); p.u4[1] = f2bf(v.y); p.u4[2] = f2bf(v.z); p.u4[3] = f2bf(v.w);
        *(unsigned long long*)&tile[r][cb + u * 4] = p.ll;
    }
    __syncthreads();
    const int n  = tid >> 2;
    const int kb = (tid & 3) * 16;
#pragma unroll
    for (int half = 0; half < 2; ++half) {
        union { ushort_t u8[8]; short8 v; } p;
#pragma unroll
        for (int j = 0; j < 8; ++j) p.u8[j] = tile[kb + half * 8 + j][n];
        *(short8*)(WT + (size_t)(n0 + n) * DMODEL + k0 + kb + half * 8) = p.v;
    }
}

// ---------------------------------------------------------------------------
// MFMA GEMM main loop (m97 structure): C += A(MxK) * WT(NxK)^T
// BM=BN=128, BK=32, 256 thr / 4 waves, each wave 64x64 (4x4 16x16x32 frags)
// ---------------------------------------------------------------------------
__device__ __forceinline__ void gemm_mainloop(
    const ushort_t* __restrict__ A, const ushort_t* __restrict__ B,
    int m0, int n0, ushort_t* At, ushort_t* Bt, f32x4 (&acc)[4][4])
{
    const int tid  = threadIdx.x;
    const int w    = tid >> 6, lane = tid & 63;
    const int l15  = lane & 15, quad = lane >> 4;
    const int wm   = w >> 1, wn = w & 1;
    const int srow = lane >> 2;        // 0..15 within a 16-row chunk
    const int skb  = (lane & 3) * 8;   // element offset (8 bf16 = 16 B)

    for (int k0 = 0; k0 < DMODEL; k0 += GBK) {
        __syncthreads();
#pragma unroll
        for (int c = 0; c < 2; ++c) {
            int chunk = w * 2 + c;
            int row = chunk * 16 + srow;
            async_copy16(A + (size_t)(m0 + row) * DMODEL + k0 + skb, At + chunk * 512);
            async_copy16(B + (size_t)(n0 + row) * DMODEL + k0 + skb, Bt + chunk * 512);
        }
        __syncthreads();

        short8 af[4], bf[4];
#pragma unroll
        for (int t = 0; t < 4; ++t) {
            af[t] = *(const short8*)(At + (wm * 64 + t * 16 + l15) * GBK + quad * 8);
            bf[t] = *(const short8*)(Bt + (wn * 64 + t * 16 + l15) * GBK + quad * 8);
        }
#pragma unroll
        for (int mt = 0; mt < 4; ++mt)
#pragma unroll
            for (int nt = 0; nt < 4; ++nt)
                acc[mt][nt] = __builtin_amdgcn_mfma_f32_16x16x32_bf16(
                    af[mt], bf[nt], acc[mt][nt], 0, 0, 0);
    }
}

// ---------------------------------------------------------------------------
// QKV projection: xb(4096x1024) @ W + b -> bf16 (B,H,T,64)
// ---------------------------------------------------------------------------
__global__ __launch_bounds__(256) void qkv_gemm(
    const ushort_t* __restrict__ xb,
    const ushort_t* __restrict__ WqT, const ushort_t* __restrict__ WkT,
    const ushort_t* __restrict__ WvT,
    const float* __restrict__ bq, const float* __restrict__ bk,
    const float* __restrict__ bv,
    ushort_t* __restrict__ Qb, ushort_t* __restrict__ Kb, ushort_t* __restrict__ Vb)
{
    const int z = blockIdx.z;
    const ushort_t* WT = (z == 0) ? WqT : (z == 1) ? WkT : WvT;
    const float* bias  = (z == 0) ? bq : (z == 1) ? bk : bv;
    ushort_t* out      = (z == 0) ? Qb : (z == 1) ? Kb : Vb;

    __shared__ ushort_t At[GBM * GBK];
    __shared__ ushort_t Bt[GBN * GBK];
    const int m0 = blockIdx.x * GBM, n0 = blockIdx.y * GBN;

    f32x4 zero = {0.f, 0.f, 0.f, 0.f};
    f32x4 acc[4][4];
#pragma unroll
    for (int i = 0; i < 4; ++i)
#pragma unroll
        for (int j = 0; j < 4; ++j) acc[i][j] = zero;

    gemm_mainloop(xb, WT, m0, n0, At, Bt, acc);

    const int tid = threadIdx.x, w = tid >> 6, lane = tid & 63;
    const int l15 = lane & 15, quad = lane >> 4;
    const int wm = w >> 1, wn = w & 1;

    float bcol[4];
#pragma unroll
    for (int nt = 0; nt < 4; ++nt) bcol[nt] = bias[n0 + wn * 64 + nt * 16 + l15];

#pragma unroll
    for (int mt = 0; mt < 4; ++mt)
#pragma unroll
        for (int reg = 0; reg < 4; ++reg) {
            int row = m0 + wm * 64 + mt * 16 + quad * 4 + reg;
            int b = row >> 11, t = row & (SEQ - 1);
#pragma unroll
            for (int nt = 0; nt < 4; ++nt) {
                int col = n0 + wn * 64 + nt * 16 + l15;
                int h = col >> 6, d = col & 63;
                out[((((size_t)b * NHEADS + h) * SEQ + t) << 6) + d] =
                    f2bf(acc[mt][nt][reg] + bcol[nt]);
            }
        }
}

// ---------------------------------------------------------------------------
// V (B,H,T,64) bf16 -> VT (B,H,64,T) bf16
// ---------------------------------------------------------------------------
__global__ __launch_bounds__(256) void vtrans_kernel(
    const ushort_t* __restrict__ Vb, ushort_t* __restrict__ VT)
{
    __shared__ ushort_t tile[64][72];
    const int t0 = blockIdx.x * 64;
    const int bh = blockIdx.y;
    const int tid = threadIdx.x;

#pragma unroll
    for (int p = 0; p < 2; ++p) {
        int t = p * 32 + (tid >> 3), dc = (tid & 7) * 8;
        *(short8*)&tile[t][dc] =
            *(const short8*)(Vb + (((size_t)bh * SEQ + t0 + t) << 6) + dc);
    }
    __syncthreads();
#pragma unroll
    for (int p = 0; p < 2; ++p) {
        int d = p * 32 + (tid >> 3), tc = (tid & 7) * 8;
        union { ushort_t u8[8]; short8 v; } pk;
#pragma unroll
        for (int j = 0; j < 8; ++j) pk.u8[j] = tile[tc + j][d];
        *(short8*)(VT + ((size_t)bh * DKH + d) * SEQ + t0 + tc) = pk.v;
    }
}

// ---------------------------------------------------------------------------
// MFMA flash attention: block = (qt,h,b), 4 waves x 16 Q-rows, 64-key tiles.
// Q,K bf16 (B,H,T,64); V^T bf16 (B,H,64,T); AO bf16 (B,T,C).
// ---------------------------------------------------------------------------
__global__ __launch_bounds__(256) void attn_kernel(
    const ushort_t* __restrict__ Qb, const ushort_t* __restrict__ Kb,
    const ushort_t* __restrict__ VT, ushort_t* __restrict__ AO)
{
    const int qt = gridDim.x - 1 - blockIdx.x;   // heavy blocks dispatch first
    const int h = blockIdx.y, b = blockIdx.z;
    const int bh = b * NHEADS + h;
    const int tid = threadIdx.x, w = tid >> 6, lane = tid & 63;
    const int l15 = lane & 15, quad = lane >> 4;

    __shared__ ushort_t Kt[64][72];      // keys x d
    __shared__ ushort_t Vt[64][72];      // d x keys
    __shared__ ushort_t Pt[4][16][72];   // per-wave P tile (private)

    const int q0 = qt * 64;
    const int qrow = q0 + w * 16 + l15;
    short8 qa[2];
#pragma unroll
    for (int ks = 0; ks < 2; ++ks)
        qa[ks] = *(const short8*)(Qb + (((size_t)bh * SEQ + qrow) << 6) + ks * 32 + quad * 8);

    const f32x4 zero = {0.f, 0.f, 0.f, 0.f};
    float m_i[4], l_i[4];
    f32x4 o[4];
#pragma unroll
    for (int r = 0; r < 4; ++r) { m_i[r] = -1e30f; l_i[r] = 0.f; }
#pragma unroll
    for (int nt = 0; nt < 4; ++nt) o[nt] = zero;

    const int srow = tid >> 3;        // 0..31
    const int sc8  = (tid & 7) * 8;

    for (int kt = 0; kt <= qt; ++kt) {
        __syncthreads();
#pragma unroll
        for (int p = 0; p < 2; ++p) {
            int key = p * 32 + srow;
            *(short8*)&Kt[key][sc8] =
                *(const short8*)(Kb + (((size_t)bh * SEQ + kt * 64 + key) << 6) + sc8);
            int d = p * 32 + srow;
            *(short8*)&Vt[d][sc8] =
                *(const short8*)(VT + ((size_t)bh * DKH + d) * SEQ + kt * 64 + sc8);
        }
        __syncthreads();

        // S = Q K^T : 16 rows x 64 keys per wave
        f32x4 sc[4];
#pragma unroll
        for (int nt = 0; nt < 4; ++nt) sc[nt] = zero;
#pragma unroll
        for (int ks = 0; ks < 2; ++ks)
#pragma unroll
            for (int nt = 0; nt < 4; ++nt) {
                short8 kf = *(const short8*)&Kt[nt * 16 + l15][ks * 32 + quad * 8];
                sc[nt] = __builtin_amdgcn_mfma_f32_16x16x32_bf16(qa[ks], kf, sc[nt], 0, 0, 0);
            }

        const bool diag = (kt == qt);
#pragma unroll
        for (int r = 0; r < 4; ++r) {
            const int qabs = q0 + w * 16 + quad * 4 + r;
            float s0[4];
#pragma unroll
            for (int nt = 0; nt < 4; ++nt) {
                float sv = sc[nt][r] * 0.125f;
                if (diag && (kt * 64 + nt * 16 + l15) > qabs) sv = -1e30f;
                s0[nt] = sv;
            }
            float mx = fmaxf(fmaxf(s0[0], s0[1]), fmaxf(s0[2], s0[3]));
#pragma unroll
            for (int off = 8; off >= 1; off >>= 1)
                mx = fmaxf(mx, __shfl_xor(mx, off, 16));
            float mn = fmaxf(m_i[r], mx);
            float alpha = __expf(m_i[r] - mn);
            float rs = 0.f;
#pragma unroll
            for (int nt = 0; nt < 4; ++nt) {
                float p = __expf(s0[nt] - mn);
                rs += p;
                Pt[w][quad * 4 + r][nt * 16 + l15] = f2bf(p);
            }
#pragma unroll
            for (int off = 8; off >= 1; off >>= 1)
                rs += __shfl_xor(rs, off, 16);
            l_i[r] = l_i[r] * alpha + rs;
            m_i[r] = mn;
#pragma unroll
            for (int nt = 0; nt < 4; ++nt) o[nt][r] *= alpha;
        }

        // O += P V  (P: wave-private LDS, no barrier needed)
#pragma unroll
        for (int cs = 0; cs < 2; ++cs) {
            short8 pf = *(const short8*)&Pt[w][l15][cs * 32 + quad * 8];
#pragma unroll
            for (int nt = 0; nt < 4; ++nt) {
                short8 vf = *(const short8*)&Vt[nt * 16 + l15][cs * 32 + quad * 8];
                o[nt] = __builtin_amdgcn_mfma_f32_16x16x32_bf16(pf, vf, o[nt], 0, 0, 0);
            }
        }
    }

#pragma unroll
    for (int r = 0; r < 4; ++r) {
        float inv = 1.0f / l_i[r];
        int t = q0 + w * 16 + quad * 4 + r;
#pragma unroll
        for (int nt = 0; nt < 4; ++nt)
            AO[((size_t)b * SEQ + t) * DMODEL + h * 64 + nt * 16 + l15] =
                f2bf(o[nt][r] * inv);
    }
}

// ---------------------------------------------------------------------------
// Output projection: AO(bf16 4096x1024) @ Wo + bo -> fp32 d_out
// ---------------------------------------------------------------------------
__global__ __launch_bounds__(256) void out_gemm(
    const ushort_t* __restrict__ AO, const ushort_t* __restrict__ WoT,
    const float* __restrict__ bo, float* __restrict__ out)
{
    __shared__ ushort_t At[GBM * GBK];
    __shared__ ushort_t Bt[GBN * GBK];
    const int m0 = blockIdx.x * GBM, n0 = blockIdx.y * GBN;

    f32x4 zero = {0.f, 0.f, 0.f, 0.f};
    f32x4 acc[4][4];
#pragma unroll
    for (int i = 0; i < 4; ++i)
#pragma unroll
        for (int j = 0; j < 4; ++j) acc[i][j] = zero;

    gemm_mainloop(AO, WoT, m0, n0, At, Bt, acc);

    const int tid = threadIdx.x, w = tid >> 6, lane = tid & 63;
    const int l15 = lane & 15, quad = lane >> 4;
    const int wm = w >> 1, wn = w & 1;

    float bcol[4];
#pragma unroll
    for (int nt = 0; nt < 4; ++nt) bcol[nt] = bo[n0 + wn * 64 + nt * 16 + l15];

#pragma unroll
    for (int mt = 0; mt < 4; ++mt)
#pragma unroll
        for (int reg = 0; reg < 4; ++reg) {
            int row = m0 + wm * 64 + mt * 16 + quad * 4 + reg;
#pragma unroll
            for (int nt = 0; nt < 4; ++nt) {
                int col = n0 + wn * 64 + nt * 16 + l15;
                out[(size_t)row * DMODEL + col] = acc[mt][nt][reg] + bcol[nt];
            }
        }
}

// ---------------------------------------------------------------------------
extern "C" void kernel_launch(void* const* d_in, const int* in_sizes, int n_in,
                              void* d_out, int out_size, void* d_ws, size_t ws_size,
                              hipStream_t stream)
{
    const float* x  = (const float*)d_in[0];
    // d_in[1] = causal mask (unused; causality hardcoded)
    const float* Wq = (const float*)d_in[2];
    const float* bq = (const float*)d_in[3];
    const float* Wk = (const float*)d_in[4];
    const float* bk = (const float*)d_in[5];
    const float* Wv = (const float*)d_in[6];
    const float* bv = (const float*)d_in[7];
    const float* Wo = (const float*)d_in[8];
    const float* bo = (const float*)d_in[9];
    float* out = (float*)d_out;

    ushort_t* ws = (ushort_t*)d_ws;
    size_t off = 0;
    ushort_t* xb  = ws + off; off += (size_t)BT * DMODEL;
    ushort_t* WqT = ws + off; off += (size_t)DMODEL * DMODEL;
    ushort_t* WkT = ws + off; off += (size_t)DMODEL * DMODEL;
    ushort_t* WvT = ws + off; off += (size_t)DMODEL * DMODEL;
    ushort_t* WoT = ws + off; off += (size_t)DMODEL * DMODEL;
    ushort_t* Qb  = ws + off; off += (size_t)BT * DMODEL;
    ushort_t* Kb  = ws + off; off += (size_t)BT * DMODEL;
    ushort_t* Vb  = ws + off; off += (size_t)BT * DMODEL;
    ushort_t* VTb = ws + off; off += (size_t)BT * DMODEL;
    ushort_t* AOb = ws + off; off += (size_t)BT * DMODEL;

    cast_x_kernel<<<(BT * DMODEL) / (256 * 8), 256, 0, stream>>>(x, xb);
    wtrans_kernel<<<dim3(16, 16, 4), 256, 0, stream>>>(
        Wq, Wk, Wv, Wo, WqT, WkT, WvT, WoT);
    qkv_gemm<<<dim3(BT / GBM, DMODEL / GBN, 3), 256, 0, stream>>>(
        xb, WqT, WkT, WvT, bq, bk, bv, Qb, Kb, Vb);
    vtrans_kernel<<<dim3(SEQ / 64, BATCH * NHEADS), 256, 0, stream>>>(Vb, VTb);
    attn_kernel<<<dim3(SEQ / 64, NHEADS, BATCH), 256, 0, stream>>>(
        Qb, Kb, VTb, AOb);
    out_gemm<<<dim3(BT / GBM, DMODEL / GBN), 256, 0, stream>>>(
        AOb, WoT, bo, out);
}